// Round 13
// baseline (285.481 us; speedup 1.0000x reference)
//
#include <hip/hip_runtime.h>
#include <hip/hip_fp16.h>

#define N_NODES 50000
#define CAP 64
#define UNR 16
#define CPAD 16   // counters padded to one 64B line each

// ---------- scatter edges into fixed-capacity buckets; padded cursor becomes degree ----------
// two independent atomic->store chains per thread for MLP; thread range = [0, half)
__global__ void k_scatter(const int* __restrict__ idx, int E,
                          int* __restrict__ cursor, int* __restrict__ esrc) {
    int t = blockIdx.x * blockDim.x + threadIdx.x;
    int half = (E + 1) >> 1;
    if (t >= half) return;
    {
        int e = t;                       // e < half <= E always
        int s = idx[e], d = idx[E + e];
        int pos = atomicAdd(&cursor[d * CPAD], 1);
        if (pos < CAP) esrc[(size_t)d * CAP + pos] = s;
    }
    {
        int e = t + half;
        if (e < E) {
            int s = idx[e], d = idx[E + e];
            int pos = atomicAdd(&cursor[d * CPAD], 1);
            if (pos < CAP) esrc[(size_t)d * CAP + pos] = s;
        }
    }
}

// ---------- dis[i] = rsqrt(deg[i] + 1), deg read from padded cursor ----------
__global__ void k_rsqrt(const int* __restrict__ degp, float* __restrict__ dis, int n) {
    int i = blockIdx.x * blockDim.x + threadIdx.x;
    if (i < n) dis[i] = rsqrtf((float)degp[i * CPAD] + 1.0f);
}

// ---------- build Wcat[128][128] = [W_mu | W_ls] ----------
__global__ void k_wcat(const float* __restrict__ wmu, const float* __restrict__ wls,
                       float* __restrict__ wcat) {
    int i = blockIdx.x * blockDim.x + threadIdx.x;
    if (i >= 128 * 128) return;
    int k = i >> 7, j = i & 127;
    wcat[i] = (j < 64) ? wmu[k * 64 + j] : wls[k * 64 + (j - 64)];
}

// ---------- C16[n,128] = rowscale[n] * (A[n,128] @ W[128,128]); A fp32/fp16, C fp16 ----------
template <bool IN_HALF>
__global__ __launch_bounds__(256) void k_gemm(const void* __restrict__ Ain,
                                              const float* __restrict__ W,
                                              const float* __restrict__ rowscale,
                                              __half* __restrict__ C, int nrows) {
    __shared__ float Ws[32][128];
    __shared__ float Xs[64][32];
    int t = threadIdx.x;
    int tx = t & 31;
    int ty = t >> 5;
    int row0 = blockIdx.x * 64;
    float acc[8][4] = {};

    for (int kb = 0; kb < 4; ++kb) {
        const float4* wsrc = (const float4*)(W + (size_t)kb * 32 * 128);
        float4* wdst = (float4*)(&Ws[0][0]);
        for (int i = t; i < 1024; i += 256) wdst[i] = wsrc[i];

        if constexpr (!IN_HALF) {
            const float* Af = (const float*)Ain;
            for (int j = t; j < 512; j += 256) {
                int r = j >> 3, c4 = j & 7;
                int row = row0 + r;
                float4 v = make_float4(0.f, 0.f, 0.f, 0.f);
                if (row < nrows)
                    v = *(const float4*)(Af + (size_t)row * 128 + kb * 32 + c4 * 4);
                *(float4*)(&Xs[r][c4 * 4]) = v;
            }
        } else {
            const __half* Ah = (const __half*)Ain;
            int r = t >> 2, c8 = (t & 3) * 8;
            int row = row0 + r;
            union { float4 f; __half2 h[4]; } u;
            u.f = make_float4(0.f, 0.f, 0.f, 0.f);
            if (row < nrows)
                u.f = *(const float4*)(Ah + (size_t)row * 128 + kb * 32 + c8);
            float* xp = &Xs[r][c8];
            #pragma unroll
            for (int q = 0; q < 4; ++q) {
                float2 f2 = __half22float2(u.h[q]);
                xp[q * 2] = f2.x;
                xp[q * 2 + 1] = f2.y;
            }
        }
        __syncthreads();

        #pragma unroll
        for (int kq = 0; kq < 8; ++kq) {
            float4 xv[8];
            #pragma unroll
            for (int r = 0; r < 8; ++r)
                xv[r] = *(const float4*)(&Xs[ty * 8 + r][kq * 4]);
            #pragma unroll
            for (int kk = 0; kk < 4; ++kk) {
                float4 w = *(const float4*)(&Ws[kq * 4 + kk][tx * 4]);
                #pragma unroll
                for (int r = 0; r < 8; ++r) {
                    float xs = (kk == 0) ? xv[r].x : (kk == 1) ? xv[r].y
                             : (kk == 2) ? xv[r].z : xv[r].w;
                    acc[r][0] = fmaf(xs, w.x, acc[r][0]);
                    acc[r][1] = fmaf(xs, w.y, acc[r][1]);
                    acc[r][2] = fmaf(xs, w.z, acc[r][2]);
                    acc[r][3] = fmaf(xs, w.w, acc[r][3]);
                }
            }
        }
        __syncthreads();
    }

    #pragma unroll
    for (int r = 0; r < 8; ++r) {
        int row = row0 + ty * 8 + r;
        if (row < nrows) {
            float s = rowscale[row];
            union { float2 f; __half2 h[2]; } o;
            o.h[0] = __float22half2_rn(make_float2(acc[r][0] * s, acc[r][1] * s));
            o.h[1] = __float22half2_rn(make_float2(acc[r][2] * s, acc[r][3] * s));
            *(float2*)(C + (size_t)row * 128 + tx * 4) = o.f;
        }
    }
}

// ---------- layer1 agg: h = relu(dis_d * (sum_{s} xw'[s] + xw'[d]) + b1) ----------
__global__ __launch_bounds__(256) void k_agg1(const int* __restrict__ degp,
                                              const int* __restrict__ esrc,
                                              const __half* __restrict__ xw,
                                              const float* __restrict__ dis,
                                              const float* __restrict__ b1,
                                              __half* __restrict__ h, int n) {
    int d = blockIdx.x * 4 + (threadIdx.x >> 6);
    int lane = threadIdx.x & 63;
    if (d >= n) return;
    const int* bucket = esrc + (size_t)d * CAP;
    int cnt = min(degp[d * CPAD], CAP);
    float ax = 0.f, ay = 0.f;
    for (int e = 0; e < cnt; e += UNR) {
        int sj[UNR]; bool okj[UNR];
        #pragma unroll
        for (int j = 0; j < UNR; ++j) {
            int ee = e + j;
            okj[j] = ee < cnt;
            sj[j] = bucket[okj[j] ? ee : 0];
        }
        __half2 v[UNR];
        #pragma unroll
        for (int j = 0; j < UNR; ++j)
            v[j] = *(const __half2*)(xw + (size_t)sj[j] * 128 + lane * 2);
        #pragma unroll
        for (int j = 0; j < UNR; ++j) {
            float2 f = __half22float2(v[j]);
            ax += okj[j] ? f.x : 0.f;
            ay += okj[j] ? f.y : 0.f;
        }
    }
    float ds = dis[d];
    float2 sv = __half22float2(*(const __half2*)(xw + (size_t)d * 128 + lane * 2));
    float2 bb = *(const float2*)(b1 + lane * 2);
    float rx = fmaxf(fmaf(ds, ax + sv.x, bb.x), 0.f);
    float ry = fmaxf(fmaf(ds, ay + sv.y, bb.y), 0.f);
    *(__half2*)(h + (size_t)d * 128 + lane * 2) = __float22half2_rn(make_float2(rx, ry));
}

// ---------- layer2 agg: out = dis_d * (sum hw'[s] + hw'[d]) + bias, split mu/logstd ----------
__global__ __launch_bounds__(256) void k_agg2(const int* __restrict__ degp,
                                              const int* __restrict__ esrc,
                                              const __half* __restrict__ hw,
                                              const float* __restrict__ dis,
                                              const float* __restrict__ bmu,
                                              const float* __restrict__ bls,
                                              float* __restrict__ out, int n) {
    int d = blockIdx.x * 4 + (threadIdx.x >> 6);
    int lane = threadIdx.x & 63;
    if (d >= n) return;
    const int* bucket = esrc + (size_t)d * CAP;
    int cnt = min(degp[d * CPAD], CAP);
    float ax = 0.f, ay = 0.f;
    for (int e = 0; e < cnt; e += UNR) {
        int sj[UNR]; bool okj[UNR];
        #pragma unroll
        for (int j = 0; j < UNR; ++j) {
            int ee = e + j;
            okj[j] = ee < cnt;
            sj[j] = bucket[okj[j] ? ee : 0];
        }
        __half2 v[UNR];
        #pragma unroll
        for (int j = 0; j < UNR; ++j)
            v[j] = *(const __half2*)(hw + (size_t)sj[j] * 128 + lane * 2);
        #pragma unroll
        for (int j = 0; j < UNR; ++j) {
            float2 f = __half22float2(v[j]);
            ax += okj[j] ? f.x : 0.f;
            ay += okj[j] ? f.y : 0.f;
        }
    }
    float ds = dis[d];
    float2 sv = __half22float2(*(const __half2*)(hw + (size_t)d * 128 + lane * 2));
    float2 bb = (lane < 32) ? *(const float2*)(bmu + lane * 2)
                            : *(const float2*)(bls + (lane - 32) * 2);
    float rx = fmaf(ds, ax + sv.x, bb.x);
    float ry = fmaf(ds, ay + sv.y, bb.y);
    float* op = (lane < 32) ? out + (size_t)d * 64 + lane * 2
                            : out + (size_t)N_NODES * 64 + (size_t)d * 64 + (lane - 32) * 2;
    *(float2*)op = make_float2(rx, ry);
}

extern "C" void kernel_launch(void* const* d_in, const int* in_sizes, int n_in,
                              void* d_out, int out_size, void* d_ws, size_t ws_size,
                              hipStream_t stream) {
    const float* x   = (const float*)d_in[0];
    const int*   idx = (const int*)d_in[1];
    const float* W1  = (const float*)d_in[2];
    const float* b1  = (const float*)d_in[3];
    const float* Wmu = (const float*)d_in[4];
    const float* bmu = (const float*)d_in[5];
    const float* Wls = (const float*)d_in[6];
    const float* bls = (const float*)d_in[7];
    int E = in_sizes[1] / 2;
    float* out = (float*)d_out;

    // workspace layout (byte offsets, 64B-aligned chunks)
    char* ws = (char*)d_ws;
    size_t off = 0;
    auto alloc = [&](size_t bytes) { void* p = ws + off; off += (bytes + 63) & ~63ull; return p; };
    int*    cursor = (int*)alloc((size_t)N_NODES * CPAD * 4);       // padded: 1 counter / 64B line
    float*  dis    = (float*)alloc(N_NODES * 4);
    float*  wcat   = (float*)alloc(16384 * 4);
    int*    esrc   = (int*)alloc((size_t)N_NODES * CAP * 4);        // 12.8 MB buckets
    __half* A16    = (__half*)alloc((size_t)N_NODES * 128 * 2);     // dis*(x@W1); reused for dis*(h@Wcat)
    __half* B16    = (__half*)alloc((size_t)N_NODES * 128 * 2);     // h
    __half* C16    = A16;                                           // alias: A16 dead after agg1

    // ---- bucket build (single atomic pass; padded cursor ends as degree) ----
    hipMemsetAsync(cursor, 0, (size_t)N_NODES * CPAD * 4, stream);
    {
        int half = (E + 1) >> 1;
        k_scatter<<<(half + 255) / 256, 256, 0, stream>>>(idx, E, cursor, esrc);
    }
    k_rsqrt<<<(N_NODES + 255) / 256, 256, 0, stream>>>(cursor, dis, N_NODES);

    // ---- layer 1 ----
    k_gemm<false><<<(N_NODES + 63) / 64, 256, 0, stream>>>(x, W1, dis, A16, N_NODES);
    k_agg1<<<(N_NODES + 3) / 4, 256, 0, stream>>>(cursor, esrc, A16, dis, b1, B16, N_NODES);

    // ---- layer 2 (mu | logstd fused) ----
    k_wcat<<<(16384 + 255) / 256, 256, 0, stream>>>(Wmu, Wls, wcat);
    k_gemm<true><<<(N_NODES + 63) / 64, 256, 0, stream>>>(B16, wcat, dis, C16, N_NODES);
    k_agg2<<<(N_NODES + 3) / 4, 256, 0, stream>>>(cursor, esrc, C16, dis, bmu, bls, out, N_NODES);
}

// Round 14
// 243.761 us; speedup vs baseline: 1.1712x; 1.1712x over previous
//
#include <hip/hip_runtime.h>
#include <hip/hip_fp16.h>

#define N_NODES 50000
#define CAP 64
#define UNR 16

typedef __attribute__((ext_vector_type(8))) _Float16 half8;
typedef __attribute__((ext_vector_type(4))) float f32x4;

// ---------- scatter edges into fixed-capacity buckets; cursor becomes degree ----------
__global__ void k_scatter(const int* __restrict__ idx, int E,
                          int* __restrict__ cursor, int* __restrict__ esrc) {
    int e = blockIdx.x * blockDim.x + threadIdx.x;
    if (e >= E) return;
    int s = idx[e], d = idx[E + e];
    int pos = atomicAdd(&cursor[d], 1);
    if (pos < CAP) esrc[(size_t)d * CAP + pos] = s;
}

// ---------- dis[i] = rsqrt(deg[i] + 1) ----------
__global__ void k_rsqrt(const int* __restrict__ deg, float* __restrict__ dis, int n) {
    int i = blockIdx.x * blockDim.x + threadIdx.x;
    if (i < n) dis[i] = rsqrtf((float)deg[i] + 1.0f);
}

// ---------- build Wcat[128][128] = [W_mu | W_ls] ----------
__global__ void k_wcat(const float* __restrict__ wmu, const float* __restrict__ wls,
                       float* __restrict__ wcat) {
    int i = blockIdx.x * blockDim.x + threadIdx.x;
    if (i >= 128 * 128) return;
    int k = i >> 7, j = i & 127;
    wcat[i] = (j < 64) ? wmu[k * 64 + j] : wls[k * 64 + (j - 64)];
}

// ---------- MFMA GEMM: C16[n,128] = rowscale[n] * (A[n,128] @ W[128,128]) ----------
// block = 256 thr (4 waves), tile 64 rows; W transposed to LDS fp16; 16x16x32 f16 MFMA
template <bool IN_HALF>
__global__ __launch_bounds__(256) void k_gemm(const void* __restrict__ Ain,
                                              const float* __restrict__ W,
                                              const float* __restrict__ rowscale,
                                              __half* __restrict__ C, int nrows) {
    __shared__ _Float16 As[64][136];   // A tile, +8 pad
    __shared__ _Float16 Wt[128][136];  // W transposed [n][k], +8 pad
    int t = threadIdx.x;
    int row0 = blockIdx.x * 64;

    // stage W transposed (fp32 -> fp16), coalesced reads
    for (int i = t; i < 16384; i += 256) {
        int k = i >> 7, n = i & 127;
        Wt[n][k] = (_Float16)W[i];
    }
    // stage A tile
    if constexpr (!IN_HALF) {
        const float* Af = (const float*)Ain;
        for (int i = t; i < 2048; i += 256) {       // 64 rows x 32 float4
            int r = i >> 5, c4 = i & 31;
            int row = row0 + r;
            float4 v = make_float4(0.f, 0.f, 0.f, 0.f);
            if (row < nrows) v = *(const float4*)(Af + (size_t)row * 128 + c4 * 4);
            _Float16* dst = &As[r][c4 * 4];
            dst[0] = (_Float16)v.x; dst[1] = (_Float16)v.y;
            dst[2] = (_Float16)v.z; dst[3] = (_Float16)v.w;
        }
    } else {
        const __half* Ah = (const __half*)Ain;
        for (int i = t; i < 1024; i += 256) {       // 64 rows x 8 half8
            int r = i >> 4, c8 = i & 15;            // 16 chunks of 8 halves per row
            int row = row0 + r;
            half8 v = {};
            if (row < nrows) v = *(const half8*)(Ah + (size_t)row * 128 + c8 * 8);
            *(half8*)&As[r][c8 * 8] = v;
        }
    }
    __syncthreads();

    int wid = t >> 6, lane = t & 63;
    int l15 = lane & 15, kg = lane >> 4;
    int koff = kg * 8;

    // A fragments for this wave's 16 rows
    half8 a[4];
    int arow = wid * 16 + l15;
    #pragma unroll
    for (int kc = 0; kc < 4; ++kc)
        a[kc] = *(const half8*)&As[arow][kc * 32 + koff];

    f32x4 acc[8];
    #pragma unroll
    for (int nt = 0; nt < 8; ++nt) acc[nt] = (f32x4){0.f, 0.f, 0.f, 0.f};

    #pragma unroll
    for (int nt = 0; nt < 8; ++nt) {
        int bcol = nt * 16 + l15;
        #pragma unroll
        for (int kc = 0; kc < 4; ++kc) {
            half8 b = *(const half8*)&Wt[bcol][kc * 32 + koff];
            acc[nt] = __builtin_amdgcn_mfma_f32_16x16x32_f16(a[kc], b, acc[nt], 0, 0, 0);
        }
    }

    // epilogue: C[row][col] = rowscale[row] * acc, col=lane&15, row=(lane>>4)*4+reg
    int rbase = row0 + wid * 16 + kg * 4;
    float rs[4];
    #pragma unroll
    for (int r = 0; r < 4; ++r)
        rs[r] = (rbase + r < nrows) ? rowscale[rbase + r] : 1.0f;
    #pragma unroll
    for (int nt = 0; nt < 8; ++nt) {
        int col = nt * 16 + l15;
        #pragma unroll
        for (int r = 0; r < 4; ++r) {
            int row = rbase + r;
            if (row < nrows)
                C[(size_t)row * 128 + col] = __float2half(acc[nt][r] * rs[r]);
        }
    }
}

// ---------- layer1 agg: h = relu(dis_d * (sum_{s} xw'[s] + xw'[d]) + b1) ----------
__global__ __launch_bounds__(256) void k_agg1(const int* __restrict__ deg,
                                              const int* __restrict__ esrc,
                                              const __half* __restrict__ xw,
                                              const float* __restrict__ dis,
                                              const float* __restrict__ b1,
                                              __half* __restrict__ h, int n) {
    int d = blockIdx.x * 4 + (threadIdx.x >> 6);
    int lane = threadIdx.x & 63;
    if (d >= n) return;
    const int* bucket = esrc + (size_t)d * CAP;
    int cnt = min(deg[d], CAP);
    float ax = 0.f, ay = 0.f;
    for (int e = 0; e < cnt; e += UNR) {
        int sj[UNR]; bool okj[UNR];
        #pragma unroll
        for (int j = 0; j < UNR; ++j) {
            int ee = e + j;
            okj[j] = ee < cnt;
            sj[j] = bucket[okj[j] ? ee : 0];
        }
        __half2 v[UNR];
        #pragma unroll
        for (int j = 0; j < UNR; ++j)
            v[j] = *(const __half2*)(xw + (size_t)sj[j] * 128 + lane * 2);
        #pragma unroll
        for (int j = 0; j < UNR; ++j) {
            float2 f = __half22float2(v[j]);
            ax += okj[j] ? f.x : 0.f;
            ay += okj[j] ? f.y : 0.f;
        }
    }
    float ds = dis[d];
    float2 sv = __half22float2(*(const __half2*)(xw + (size_t)d * 128 + lane * 2));
    float2 bb = *(const float2*)(b1 + lane * 2);
    float rx = fmaxf(fmaf(ds, ax + sv.x, bb.x), 0.f);
    float ry = fmaxf(fmaf(ds, ay + sv.y, bb.y), 0.f);
    *(__half2*)(h + (size_t)d * 128 + lane * 2) = __float22half2_rn(make_float2(rx, ry));
}

// ---------- layer2 agg: out = dis_d * (sum hw'[s] + hw'[d]) + bias, split mu/logstd ----------
__global__ __launch_bounds__(256) void k_agg2(const int* __restrict__ deg,
                                              const int* __restrict__ esrc,
                                              const __half* __restrict__ hw,
                                              const float* __restrict__ dis,
                                              const float* __restrict__ bmu,
                                              const float* __restrict__ bls,
                                              float* __restrict__ out, int n) {
    int d = blockIdx.x * 4 + (threadIdx.x >> 6);
    int lane = threadIdx.x & 63;
    if (d >= n) return;
    const int* bucket = esrc + (size_t)d * CAP;
    int cnt = min(deg[d], CAP);
    float ax = 0.f, ay = 0.f;
    for (int e = 0; e < cnt; e += UNR) {
        int sj[UNR]; bool okj[UNR];
        #pragma unroll
        for (int j = 0; j < UNR; ++j) {
            int ee = e + j;
            okj[j] = ee < cnt;
            sj[j] = bucket[okj[j] ? ee : 0];
        }
        __half2 v[UNR];
        #pragma unroll
        for (int j = 0; j < UNR; ++j)
            v[j] = *(const __half2*)(hw + (size_t)sj[j] * 128 + lane * 2);
        #pragma unroll
        for (int j = 0; j < UNR; ++j) {
            float2 f = __half22float2(v[j]);
            ax += okj[j] ? f.x : 0.f;
            ay += okj[j] ? f.y : 0.f;
        }
    }
    float ds = dis[d];
    float2 sv = __half22float2(*(const __half2*)(hw + (size_t)d * 128 + lane * 2));
    float2 bb = (lane < 32) ? *(const float2*)(bmu + lane * 2)
                            : *(const float2*)(bls + (lane - 32) * 2);
    float rx = fmaf(ds, ax + sv.x, bb.x);
    float ry = fmaf(ds, ay + sv.y, bb.y);
    float* op = (lane < 32) ? out + (size_t)d * 64 + lane * 2
                            : out + (size_t)N_NODES * 64 + (size_t)d * 64 + (lane - 32) * 2;
    *(float2*)op = make_float2(rx, ry);
}

extern "C" void kernel_launch(void* const* d_in, const int* in_sizes, int n_in,
                              void* d_out, int out_size, void* d_ws, size_t ws_size,
                              hipStream_t stream) {
    const float* x   = (const float*)d_in[0];
    const int*   idx = (const int*)d_in[1];
    const float* W1  = (const float*)d_in[2];
    const float* b1  = (const float*)d_in[3];
    const float* Wmu = (const float*)d_in[4];
    const float* bmu = (const float*)d_in[5];
    const float* Wls = (const float*)d_in[6];
    const float* bls = (const float*)d_in[7];
    int E = in_sizes[1] / 2;
    float* out = (float*)d_out;

    // workspace layout (byte offsets, 64B-aligned chunks)
    char* ws = (char*)d_ws;
    size_t off = 0;
    auto alloc = [&](size_t bytes) { void* p = ws + off; off += (bytes + 63) & ~63ull; return p; };
    int*    cursor = (int*)alloc(N_NODES * 4);                      // becomes degree
    float*  dis    = (float*)alloc(N_NODES * 4);
    float*  wcat   = (float*)alloc(16384 * 4);
    int*    esrc   = (int*)alloc((size_t)N_NODES * CAP * 4);        // 12.8 MB buckets
    __half* A16    = (__half*)alloc((size_t)N_NODES * 128 * 2);     // dis*(x@W1); reused for dis*(h@Wcat)
    __half* B16    = (__half*)alloc((size_t)N_NODES * 128 * 2);     // h
    __half* C16    = A16;                                           // alias: A16 dead after agg1

    // ---- bucket build (single atomic pass; cursor ends as degree) ----
    hipMemsetAsync(cursor, 0, N_NODES * sizeof(int), stream);
    k_scatter<<<(E + 255) / 256, 256, 0, stream>>>(idx, E, cursor, esrc);
    k_rsqrt<<<(N_NODES + 255) / 256, 256, 0, stream>>>(cursor, dis, N_NODES);

    // ---- layer 1 ----
    k_gemm<false><<<(N_NODES + 63) / 64, 256, 0, stream>>>(x, W1, dis, A16, N_NODES);
    k_agg1<<<(N_NODES + 3) / 4, 256, 0, stream>>>(cursor, esrc, A16, dis, b1, B16, N_NODES);

    // ---- layer 2 (mu | logstd fused) ----
    k_wcat<<<(16384 + 255) / 256, 256, 0, stream>>>(Wmu, Wls, wcat);
    k_gemm<true><<<(N_NODES + 63) / 64, 256, 0, stream>>>(B16, wcat, dis, C16, N_NODES);
    k_agg2<<<(N_NODES + 3) / 4, 256, 0, stream>>>(cursor, esrc, C16, dis, bmu, bls, out, N_NODES);
}